// Round 1
// baseline (725.111 us; speedup 1.0000x reference)
//
#include <hip/hip_runtime.h>

#define N_NODES 50000
#define N_EDGES 800000
#define IN_F    512
#define NH      4
#define DH      64
#define HD      256   // NH*DH
#define NEG     0.2f

// ---------------- zero int buffer ----------------
__global__ void zero_kernel(int* __restrict__ p, int n) {
    int i = blockIdx.x * blockDim.x + threadIdx.x;
    if (i < n) p[i] = 0;
}

// ---------------- fp32 GEMM: ft = feat @ W  [M,512]x[512,256] ----------------
// 64x64 block tile, BK=16, 256 threads, 4x4 micro-tile per thread.
#define BM 64
#define BN 64
#define BK 16
__global__ __launch_bounds__(256) void gemm_kernel(const float* __restrict__ A,
                                                   const float* __restrict__ B,
                                                   float* __restrict__ C, int M) {
    __shared__ float As[BK][BM];   // transposed A tile: As[k][m]
    __shared__ float Bs[BK][BN];   // Bs[k][n]

    const int tid = threadIdx.x;
    const int tx  = tid & 15;      // 16 col-groups
    const int ty  = tid >> 4;      // 16 row-groups
    const int row0 = blockIdx.x * BM;
    const int col0 = blockIdx.y * BN;

    // A-tile load mapping: 64 rows x 16 cols, float4 per thread
    const int arow  = tid >> 2;          // 0..63
    const int acol4 = (tid & 3) * 4;     // 0,4,8,12
    // B-tile load mapping: 16 rows x 64 cols, float4 per thread
    const int brow  = tid >> 4;          // 0..15
    const int bcol4 = (tid & 15) * 4;

    float acc[4][4] = {};

    for (int kt = 0; kt < IN_F; kt += BK) {
        float4 av = make_float4(0.f, 0.f, 0.f, 0.f);
        int gr = row0 + arow;
        if (gr < M) av = *(const float4*)(A + (size_t)gr * IN_F + kt + acol4);
        As[acol4 + 0][arow] = av.x;
        As[acol4 + 1][arow] = av.y;
        As[acol4 + 2][arow] = av.z;
        As[acol4 + 3][arow] = av.w;

        float4 bv = *(const float4*)(B + (size_t)(kt + brow) * HD + col0 + bcol4);
        *(float4*)(&Bs[brow][bcol4]) = bv;

        __syncthreads();
#pragma unroll
        for (int k = 0; k < BK; k++) {
            float a[4], b[4];
#pragma unroll
            for (int i = 0; i < 4; i++) a[i] = As[k][ty * 4 + i];
#pragma unroll
            for (int j = 0; j < 4; j++) b[j] = Bs[k][tx * 4 + j];
#pragma unroll
            for (int i = 0; i < 4; i++)
#pragma unroll
                for (int j = 0; j < 4; j++) acc[i][j] += a[i] * b[j];
        }
        __syncthreads();
    }

#pragma unroll
    for (int i = 0; i < 4; i++) {
        int gr = row0 + ty * 4 + i;
        if (gr < M) {
            float4 o = make_float4(acc[i][0], acc[i][1], acc[i][2], acc[i][3]);
            *(float4*)(C + (size_t)gr * HD + col0 + tx * 4) = o;
        }
    }
}

// ---------------- el/er: one wave per (node, head), 64-lane dot ----------------
__global__ __launch_bounds__(256) void el_er_kernel(const float* __restrict__ ft,
                                                    const float* __restrict__ attn_l,
                                                    const float* __restrict__ attn_r,
                                                    float* __restrict__ el,
                                                    float* __restrict__ er) {
    int wid  = (blockIdx.x * blockDim.x + threadIdx.x) >> 6;  // (n*NH + h)
    int lane = threadIdx.x & 63;
    if (wid >= N_NODES * NH) return;
    int n = wid >> 2;
    int h = wid & 3;
    float f  = ft[(size_t)n * HD + h * DH + lane];
    float pl = f * attn_l[h * DH + lane];
    float pr = f * attn_r[h * DH + lane];
#pragma unroll
    for (int off = 32; off > 0; off >>= 1) {
        pl += __shfl_down(pl, off);
        pr += __shfl_down(pr, off);
    }
    if (lane == 0) { el[wid] = pl; er[wid] = pr; }
}

// ---------------- edge scores: exp(leaky_relu(el[src]+er[dst])), count by dst --
__device__ __forceinline__ float lrelu_exp(float x) {
    float y = (x > 0.f) ? x : NEG * x;
    return __expf(y);
}

__global__ __launch_bounds__(256) void edge_kernel(const int* __restrict__ src,
                                                   const int* __restrict__ dst,
                                                   const float* __restrict__ el,
                                                   const float* __restrict__ er,
                                                   float* __restrict__ exp_e,
                                                   int* __restrict__ counts) {
    int e = blockIdx.x * blockDim.x + threadIdx.x;
    if (e >= N_EDGES) return;
    int u = src[e], v = dst[e];
    float4 l = *(const float4*)(el + (size_t)u * NH);
    float4 r = *(const float4*)(er + (size_t)v * NH);
    float4 s;
    s.x = lrelu_exp(l.x + r.x);
    s.y = lrelu_exp(l.y + r.y);
    s.z = lrelu_exp(l.z + r.z);
    s.w = lrelu_exp(l.w + r.w);
    *(float4*)(exp_e + (size_t)e * NH) = s;
    atomicAdd(&counts[v], 1);
}

// ---------------- single-block chunked exclusive scan of counts ----------------
__global__ __launch_bounds__(256) void scan_kernel(const int* __restrict__ counts,
                                                   int* __restrict__ offsets,
                                                   int* __restrict__ cursor) {
    __shared__ int sums[256];
    const int tid = threadIdx.x;
    const int CH  = (N_NODES + 255) / 256;   // 196
    int begin = tid * CH;
    int end   = begin + CH; if (end > N_NODES) end = N_NODES;
    if (begin > N_NODES) begin = N_NODES;

    int s = 0;
    for (int i = begin; i < end; i++) s += counts[i];
    sums[tid] = s;
    __syncthreads();
    // inclusive scan (Hillis-Steele)
    for (int off = 1; off < 256; off <<= 1) {
        int v   = sums[tid];
        int add = (tid >= off) ? sums[tid - off] : 0;
        __syncthreads();
        sums[tid] = v + add;
        __syncthreads();
    }
    int run = (tid > 0) ? sums[tid - 1] : 0;
    for (int i = begin; i < end; i++) {
        int c = counts[i];
        offsets[i] = run;
        cursor[i]  = run;
        run += c;
    }
    if (tid == 255) offsets[N_NODES] = run;  // == N_EDGES
}

// ---------------- fill CSR edge list ----------------
__global__ __launch_bounds__(256) void fill_kernel(const int* __restrict__ dst,
                                                   int* __restrict__ cursor,
                                                   int* __restrict__ edge_list) {
    int e = blockIdx.x * blockDim.x + threadIdx.x;
    if (e >= N_EDGES) return;
    int pos = atomicAdd(&cursor[dst[e]], 1);
    edge_list[pos] = e;
}

// ---------------- aggregation: one wave per destination node ----------------
__global__ __launch_bounds__(256) void agg_kernel(const float* __restrict__ ft,
                                                  const float* __restrict__ exp_e,
                                                  const int* __restrict__ offsets,
                                                  const int* __restrict__ edge_list,
                                                  const int* __restrict__ src,
                                                  float* __restrict__ out) {
    int wv   = (blockIdx.x * blockDim.x + threadIdx.x) >> 6;  // node id
    int lane = threadIdx.x & 63;
    if (wv >= N_NODES) return;

    int beg = offsets[wv];
    int end = offsets[wv + 1];
    int h   = lane >> 4;   // head owning this lane's 4 columns

    float4 acc = make_float4(0.f, 0.f, 0.f, 0.f);
    float dsum = 0.f;

    for (int p = beg; p < end; p++) {
        int e = edge_list[p];
        int u = src[e];
        float4 w4 = *(const float4*)(exp_e + (size_t)e * NH);
        float w = (h == 0) ? w4.x : (h == 1) ? w4.y : (h == 2) ? w4.z : w4.w;
        float4 f = *(const float4*)(ft + (size_t)u * HD + lane * 4);
        acc.x += w * f.x;
        acc.y += w * f.y;
        acc.z += w * f.z;
        acc.w += w * f.w;
        dsum += w;
    }
    float inv = (dsum > 0.f) ? (1.f / dsum) : 0.f;
    acc.x *= inv; acc.y *= inv; acc.z *= inv; acc.w *= inv;
    *(float4*)(out + (size_t)wv * HD + lane * 4) = acc;
}

// ---------------- launch ----------------
extern "C" void kernel_launch(void* const* d_in, const int* in_sizes, int n_in,
                              void* d_out, int out_size, void* d_ws, size_t ws_size,
                              hipStream_t stream) {
    const float* feat   = (const float*)d_in[0];
    const float* W      = (const float*)d_in[1];
    const float* attn_l = (const float*)d_in[2];
    const float* attn_r = (const float*)d_in[3];
    const int*   src    = (const int*)d_in[4];
    const int*   dst    = (const int*)d_in[5];
    float* out = (float*)d_out;

    char* p = (char*)d_ws;
    auto alloc = [&](size_t bytes) -> char* {
        char* r = p;
        p += (bytes + 255) & ~(size_t)255;
        return r;
    };
    float* ft        = (float*)alloc((size_t)N_NODES * HD * 4);     // 51.2 MB
    float* el        = (float*)alloc((size_t)N_NODES * NH * 4);
    float* er        = (float*)alloc((size_t)N_NODES * NH * 4);
    float* exp_e     = (float*)alloc((size_t)N_EDGES * NH * 4);     // 12.8 MB
    int*   counts    = (int*)alloc((size_t)N_NODES * 4);
    int*   offsets   = (int*)alloc((size_t)(N_NODES + 1) * 4);
    int*   cursor    = (int*)alloc((size_t)N_NODES * 4);
    int*   edge_list = (int*)alloc((size_t)N_EDGES * 4);            // 3.2 MB

    // 1. zero counts
    zero_kernel<<<(N_NODES + 255) / 256, 256, 0, stream>>>(counts, N_NODES);

    // 2. ft = feat @ W
    dim3 ggrid((N_NODES + BM - 1) / BM, HD / BN);
    gemm_kernel<<<ggrid, 256, 0, stream>>>(feat, W, ft, N_NODES);

    // 3. el / er
    el_er_kernel<<<(N_NODES * NH) / 4, 256, 0, stream>>>(ft, attn_l, attn_r, el, er);

    // 4. edge scores + per-dst counts
    edge_kernel<<<(N_EDGES + 255) / 256, 256, 0, stream>>>(src, dst, el, er, exp_e, counts);

    // 5. exclusive scan -> offsets, cursor
    scan_kernel<<<1, 256, 0, stream>>>(counts, offsets, cursor);

    // 6. fill CSR edge list
    fill_kernel<<<(N_EDGES + 255) / 256, 256, 0, stream>>>(dst, cursor, edge_list);

    // 7. aggregate per destination node (normalization fused)
    agg_kernel<<<(N_NODES + 3) / 4, 256, 0, stream>>>(ft, exp_e, offsets, edge_list, src, out);
}

// Round 2
// 547.233 us; speedup vs baseline: 1.3251x; 1.3251x over previous
//
#include <hip/hip_runtime.h>

#define N_NODES 50000
#define N_EDGES 800000
#define IN_F    512
#define NH      4
#define DH      64
#define HD      256   // NH*DH
#define NEG     0.2f

typedef __attribute__((ext_vector_type(8))) short bf16x8;
typedef __attribute__((ext_vector_type(4))) float f32x4;

__device__ __forceinline__ unsigned short f2bf(float x) {
    unsigned u = __float_as_uint(x);
    unsigned r = (u + 0x7FFFu + ((u >> 16) & 1u)) >> 16;  // RNE
    return (unsigned short)r;
}

// ---------------- zero int buffer ----------------
__global__ void zero_kernel(int* __restrict__ p, int n) {
    int i = blockIdx.x * blockDim.x + threadIdx.x;
    if (i < n) p[i] = 0;
}

// ---------------- per-dst edge counts ----------------
__global__ __launch_bounds__(256) void count_kernel(const int* __restrict__ dst,
                                                    int* __restrict__ counts) {
    int e = blockIdx.x * blockDim.x + threadIdx.x;
    if (e < N_EDGES) atomicAdd(&counts[dst[e]], 1);
}

// ---------------- W [512][256] fp32 -> Wt [256][512] bf16 ----------------
__global__ __launch_bounds__(256) void wt_kernel(const float* __restrict__ W,
                                                 unsigned short* __restrict__ Wtb) {
    int i = blockIdx.x * blockDim.x + threadIdx.x;  // over 512*256
    if (i >= IN_F * HD) return;
    int k = i >> 8;        // 0..511
    int n = i & 255;       // 0..255
    Wtb[(size_t)n * IN_F + k] = f2bf(W[i]);
}

// ---------------- bf16 MFMA GEMM: ft = feat @ W  (A converted on the fly) -----
// 128x128 tile, BK=64, 4 waves (2x2), each wave 64x64 via 4x4 of 16x16x32 MFMA.
#define LDP 72   // padded LDS row stride in shorts (64 data + 8 pad)
__global__ __launch_bounds__(256) void gemm_kernel(const float* __restrict__ A,
                                                   const unsigned short* __restrict__ Wtb,
                                                   float* __restrict__ C) {
    __shared__ short A_s[128][LDP];
    __shared__ short B_s[128][LDP];

    const int tid  = threadIdx.x;
    const int lane = tid & 63;
    const int wave = tid >> 6;
    const int wr   = wave >> 1;     // 0..1 row half
    const int wc   = wave & 1;      // 0..1 col half
    const int lm   = lane & 15;
    const int quad = lane >> 4;
    const int row0 = blockIdx.x * 128;
    const int col0 = blockIdx.y * 128;

    f32x4 acc[4][4] = {};

    for (int kt = 0; kt < IN_F; kt += 64) {
        // stage A (fp32 -> bf16 in-register), 128 rows x 64 cols
#pragma unroll
        for (int it = 0; it < 4; it++) {
            int gid = it * 256 + tid;
            int row = gid >> 3;
            int c8  = (gid & 7) * 8;
            int grow = row0 + row;
            float4 v0 = make_float4(0.f, 0.f, 0.f, 0.f);
            float4 v1 = v0;
            if (grow < N_NODES) {
                const float* ap = A + (size_t)grow * IN_F + kt + c8;
                v0 = *(const float4*)(ap);
                v1 = *(const float4*)(ap + 4);
            }
            bf16x8 s;
            s[0] = (short)f2bf(v0.x); s[1] = (short)f2bf(v0.y);
            s[2] = (short)f2bf(v0.z); s[3] = (short)f2bf(v0.w);
            s[4] = (short)f2bf(v1.x); s[5] = (short)f2bf(v1.y);
            s[6] = (short)f2bf(v1.z); s[7] = (short)f2bf(v1.w);
            *(bf16x8*)(&A_s[row][c8]) = s;
        }
        // stage B (already bf16, transposed): rows are output cols
#pragma unroll
        for (int it = 0; it < 4; it++) {
            int gid = it * 256 + tid;
            int row = gid >> 3;
            int c8  = (gid & 7) * 8;
            *(bf16x8*)(&B_s[row][c8]) =
                *(const bf16x8*)(Wtb + (size_t)(col0 + row) * IN_F + kt + c8);
        }
        __syncthreads();

#pragma unroll
        for (int kk = 0; kk < 64; kk += 32) {
            bf16x8 af[4], bfr[4];
#pragma unroll
            for (int i = 0; i < 4; i++)
                af[i] = *(const bf16x8*)(&A_s[wr * 64 + i * 16 + lm][kk + quad * 8]);
#pragma unroll
            for (int j = 0; j < 4; j++)
                bfr[j] = *(const bf16x8*)(&B_s[wc * 64 + j * 16 + lm][kk + quad * 8]);
#pragma unroll
            for (int i = 0; i < 4; i++)
#pragma unroll
                for (int j = 0; j < 4; j++)
                    acc[i][j] = __builtin_amdgcn_mfma_f32_16x16x32_bf16(
                        af[i], bfr[j], acc[i][j], 0, 0, 0);
        }
        __syncthreads();
    }

    // C/D layout: col = lane&15, row = quad*4 + reg
#pragma unroll
    for (int i = 0; i < 4; i++) {
#pragma unroll
        for (int j = 0; j < 4; j++) {
            int gcol = col0 + wc * 64 + j * 16 + lm;
#pragma unroll
            for (int r = 0; r < 4; r++) {
                int grow = row0 + wr * 64 + i * 16 + quad * 4 + r;
                if (grow < N_NODES)
                    C[(size_t)grow * HD + gcol] = acc[i][j][r];
            }
        }
    }
}

// ---------------- el/er: one wave per (node, head), 64-lane dot ----------------
__global__ __launch_bounds__(256) void el_er_kernel(const float* __restrict__ ft,
                                                    const float* __restrict__ attn_l,
                                                    const float* __restrict__ attn_r,
                                                    float* __restrict__ el,
                                                    float* __restrict__ er) {
    int wid  = (blockIdx.x * blockDim.x + threadIdx.x) >> 6;  // (n*NH + h)
    int lane = threadIdx.x & 63;
    if (wid >= N_NODES * NH) return;
    int n = wid >> 2;
    int h = wid & 3;
    float f  = ft[(size_t)n * HD + h * DH + lane];
    float pl = f * attn_l[h * DH + lane];
    float pr = f * attn_r[h * DH + lane];
#pragma unroll
    for (int off = 32; off > 0; off >>= 1) {
        pl += __shfl_down(pl, off);
        pr += __shfl_down(pr, off);
    }
    if (lane == 0) { el[wid] = pl; er[wid] = pr; }
}

// ---------------- chunked exclusive scan of counts (single block) --------------
__global__ __launch_bounds__(256) void scan_kernel(const int* __restrict__ counts,
                                                   int* __restrict__ offsets,
                                                   int* __restrict__ cursor) {
    __shared__ int sums[256];
    const int tid = threadIdx.x;
    const int CH  = (N_NODES + 255) / 256;
    int begin = tid * CH;
    int end   = begin + CH; if (end > N_NODES) end = N_NODES;
    if (begin > N_NODES) begin = N_NODES;

    int s = 0;
    for (int i = begin; i < end; i++) s += counts[i];
    sums[tid] = s;
    __syncthreads();
    for (int off = 1; off < 256; off <<= 1) {
        int v   = sums[tid];
        int add = (tid >= off) ? sums[tid - off] : 0;
        __syncthreads();
        sums[tid] = v + add;
        __syncthreads();
    }
    int run = (tid > 0) ? sums[tid - 1] : 0;
    for (int i = begin; i < end; i++) {
        int c = counts[i];
        offsets[i] = run;
        cursor[i]  = run;
        run += c;
    }
    if (tid == 255) offsets[N_NODES] = run;
}

// ---------------- edge scores placed directly in CSR order --------------------
__device__ __forceinline__ float lrelu_exp(float x) {
    float y = (x > 0.f) ? x : NEG * x;
    return __expf(y);
}

__global__ __launch_bounds__(256) void edge_place_kernel(const int* __restrict__ src,
                                                         const int* __restrict__ dst,
                                                         const float* __restrict__ el,
                                                         const float* __restrict__ er,
                                                         int* __restrict__ cursor,
                                                         int* __restrict__ srcs,
                                                         float* __restrict__ w4s) {
    int e = blockIdx.x * blockDim.x + threadIdx.x;
    if (e >= N_EDGES) return;
    int u = src[e], v = dst[e];
    float4 l = *(const float4*)(el + (size_t)u * NH);
    float4 r = *(const float4*)(er + (size_t)v * NH);
    float4 s;
    s.x = lrelu_exp(l.x + r.x);
    s.y = lrelu_exp(l.y + r.y);
    s.z = lrelu_exp(l.z + r.z);
    s.w = lrelu_exp(l.w + r.w);
    int pos = atomicAdd(&cursor[v], 1);
    srcs[pos] = u;
    *(float4*)(w4s + (size_t)pos * NH) = s;
}

// ---------------- aggregation: one wave per destination node ------------------
__global__ __launch_bounds__(256) void agg_kernel(const float* __restrict__ ft,
                                                  const float* __restrict__ w4s,
                                                  const int* __restrict__ srcs,
                                                  const int* __restrict__ offsets,
                                                  float* __restrict__ out) {
    int wv   = (blockIdx.x * blockDim.x + threadIdx.x) >> 6;  // node id
    int lane = threadIdx.x & 63;
    if (wv >= N_NODES) return;

    int beg = offsets[wv];
    int end = offsets[wv + 1];
    int h   = lane >> 4;

    float4 acc = make_float4(0.f, 0.f, 0.f, 0.f);
    float dsum = 0.f;

    if (beg < end) {
        int u = srcs[beg];
        for (int p = beg; p < end; p++) {
            int un  = (p + 1 < end) ? srcs[p + 1] : 0;    // prefetch next index
            float w = w4s[(size_t)p * NH + h];            // broadcast, L1-hot
            float4 f = *(const float4*)(ft + (size_t)u * HD + lane * 4);
            acc.x += w * f.x;
            acc.y += w * f.y;
            acc.z += w * f.z;
            acc.w += w * f.w;
            dsum += w;
            u = un;
        }
    }
    float inv = (dsum > 0.f) ? (1.f / dsum) : 0.f;
    acc.x *= inv; acc.y *= inv; acc.z *= inv; acc.w *= inv;
    *(float4*)(out + (size_t)wv * HD + lane * 4) = acc;
}

// ---------------- launch ----------------
extern "C" void kernel_launch(void* const* d_in, const int* in_sizes, int n_in,
                              void* d_out, int out_size, void* d_ws, size_t ws_size,
                              hipStream_t stream) {
    const float* feat   = (const float*)d_in[0];
    const float* W      = (const float*)d_in[1];
    const float* attn_l = (const float*)d_in[2];
    const float* attn_r = (const float*)d_in[3];
    const int*   src    = (const int*)d_in[4];
    const int*   dst    = (const int*)d_in[5];
    float* out = (float*)d_out;

    char* p = (char*)d_ws;
    auto alloc = [&](size_t bytes) -> char* {
        char* r = p;
        p += (bytes + 255) & ~(size_t)255;
        return r;
    };
    float*          ft      = (float*)alloc((size_t)N_NODES * HD * 4);   // 51.2 MB
    unsigned short* Wtb     = (unsigned short*)alloc((size_t)IN_F * HD * 2);
    float*          el      = (float*)alloc((size_t)N_NODES * NH * 4);
    float*          er      = (float*)alloc((size_t)N_NODES * NH * 4);
    float*          w4s     = (float*)alloc((size_t)N_EDGES * NH * 4);   // 12.8 MB
    int*            srcs    = (int*)alloc((size_t)N_EDGES * 4);          // 3.2 MB
    int*            counts  = (int*)alloc((size_t)N_NODES * 4);
    int*            offsets = (int*)alloc((size_t)(N_NODES + 1) * 4);
    int*            cursor  = (int*)alloc((size_t)N_NODES * 4);

    // 1. zero counts
    zero_kernel<<<(N_NODES + 255) / 256, 256, 0, stream>>>(counts, N_NODES);
    // 2. per-dst counts
    count_kernel<<<(N_EDGES + 255) / 256, 256, 0, stream>>>(dst, counts);
    // 3. W -> Wt bf16
    wt_kernel<<<(IN_F * HD + 255) / 256, 256, 0, stream>>>(W, Wtb);
    // 4. ft = feat @ W (bf16 MFMA)
    dim3 ggrid((N_NODES + 127) / 128, HD / 128);
    gemm_kernel<<<ggrid, 256, 0, stream>>>(feat, Wtb, ft);
    // 5. el / er
    el_er_kernel<<<(N_NODES * NH) / 4, 256, 0, stream>>>(ft, attn_l, attn_r, el, er);
    // 6. scan -> offsets, cursor
    scan_kernel<<<1, 256, 0, stream>>>(counts, offsets, cursor);
    // 7. edge scores placed in CSR order
    edge_place_kernel<<<(N_EDGES + 255) / 256, 256, 0, stream>>>(src, dst, el, er,
                                                                 cursor, srcs, w4s);
    // 8. aggregate per destination node (normalization fused)
    agg_kernel<<<(N_NODES + 3) / 4, 256, 0, stream>>>(ft, w4s, srcs, offsets, out);
}

// Round 3
// 435.349 us; speedup vs baseline: 1.6656x; 1.2570x over previous
//
#include <hip/hip_runtime.h>

#define N_NODES 50000
#define N_EDGES 800000
#define IN_F    512
#define NH      4
#define DH      64
#define HD      256   // NH*DH
#define NEG     0.2f
#define NB      ((N_NODES + 255) / 256)   // 196 scan blocks

typedef __attribute__((ext_vector_type(8))) short bf16x8;
typedef __attribute__((ext_vector_type(4))) float f32x4;

__device__ __forceinline__ unsigned short f2bf(float x) {
    unsigned u = __float_as_uint(x);
    unsigned r = (u + 0x7FFFu + ((u >> 16) & 1u)) >> 16;  // RNE
    return (unsigned short)r;
}

// ---------------- zero int buffer ----------------
__global__ void zero_kernel(int* __restrict__ p, int n) {
    int i = blockIdx.x * blockDim.x + threadIdx.x;
    if (i < n) p[i] = 0;
}

// ---------------- per-dst edge counts ----------------
__global__ __launch_bounds__(256) void count_kernel(const int* __restrict__ dst,
                                                    int* __restrict__ counts) {
    int e = blockIdx.x * blockDim.x + threadIdx.x;
    if (e < N_EDGES) atomicAdd(&counts[dst[e]], 1);
}

// ---------------- W [512][256] fp32 -> Wt [256][512] bf16 ----------------
__global__ __launch_bounds__(256) void wt_kernel(const float* __restrict__ W,
                                                 unsigned short* __restrict__ Wtb) {
    int i = blockIdx.x * blockDim.x + threadIdx.x;  // over 512*256
    if (i >= IN_F * HD) return;
    int k = i >> 8;        // 0..511
    int n = i & 255;       // 0..255
    Wtb[(size_t)n * IN_F + k] = f2bf(W[i]);
}

// ---------------- bf16 MFMA GEMM: ft = feat @ W  (A converted on the fly) -----
// 128x128 tile, BK=64, 4 waves (2x2), each wave 64x64 via 4x4 of 16x16x32 MFMA.
#define LDP 72   // padded LDS row stride in shorts (64 data + 8 pad)
__global__ __launch_bounds__(256) void gemm_kernel(const float* __restrict__ A,
                                                   const unsigned short* __restrict__ Wtb,
                                                   float* __restrict__ C) {
    __shared__ short A_s[128][LDP];
    __shared__ short B_s[128][LDP];

    const int tid  = threadIdx.x;
    const int lane = tid & 63;
    const int wave = tid >> 6;
    const int wr   = wave >> 1;     // 0..1 row half
    const int wc   = wave & 1;      // 0..1 col half
    const int lm   = lane & 15;
    const int quad = lane >> 4;
    const int row0 = blockIdx.x * 128;
    const int col0 = blockIdx.y * 128;

    f32x4 acc[4][4] = {};

    for (int kt = 0; kt < IN_F; kt += 64) {
        // stage A (fp32 -> bf16 in-register), 128 rows x 64 cols
#pragma unroll
        for (int it = 0; it < 4; it++) {
            int gid = it * 256 + tid;
            int row = gid >> 3;
            int c8  = (gid & 7) * 8;
            int grow = row0 + row;
            float4 v0 = make_float4(0.f, 0.f, 0.f, 0.f);
            float4 v1 = v0;
            if (grow < N_NODES) {
                const float* ap = A + (size_t)grow * IN_F + kt + c8;
                v0 = *(const float4*)(ap);
                v1 = *(const float4*)(ap + 4);
            }
            bf16x8 s;
            s[0] = (short)f2bf(v0.x); s[1] = (short)f2bf(v0.y);
            s[2] = (short)f2bf(v0.z); s[3] = (short)f2bf(v0.w);
            s[4] = (short)f2bf(v1.x); s[5] = (short)f2bf(v1.y);
            s[6] = (short)f2bf(v1.z); s[7] = (short)f2bf(v1.w);
            *(bf16x8*)(&A_s[row][c8]) = s;
        }
        // stage B (already bf16, transposed): rows are output cols
#pragma unroll
        for (int it = 0; it < 4; it++) {
            int gid = it * 256 + tid;
            int row = gid >> 3;
            int c8  = (gid & 7) * 8;
            *(bf16x8*)(&B_s[row][c8]) =
                *(const bf16x8*)(Wtb + (size_t)(col0 + row) * IN_F + kt + c8);
        }
        __syncthreads();

#pragma unroll
        for (int kk = 0; kk < 64; kk += 32) {
            bf16x8 af[4], bfr[4];
#pragma unroll
            for (int i = 0; i < 4; i++)
                af[i] = *(const bf16x8*)(&A_s[wr * 64 + i * 16 + lm][kk + quad * 8]);
#pragma unroll
            for (int j = 0; j < 4; j++)
                bfr[j] = *(const bf16x8*)(&B_s[wc * 64 + j * 16 + lm][kk + quad * 8]);
#pragma unroll
            for (int i = 0; i < 4; i++)
#pragma unroll
                for (int j = 0; j < 4; j++)
                    acc[i][j] = __builtin_amdgcn_mfma_f32_16x16x32_bf16(
                        af[i], bfr[j], acc[i][j], 0, 0, 0);
        }
        __syncthreads();
    }

    // C/D layout: col = lane&15, row = quad*4 + reg
#pragma unroll
    for (int i = 0; i < 4; i++) {
#pragma unroll
        for (int j = 0; j < 4; j++) {
            int gcol = col0 + wc * 64 + j * 16 + lm;
#pragma unroll
            for (int r = 0; r < 4; r++) {
                int grow = row0 + wr * 64 + i * 16 + quad * 4 + r;
                if (grow < N_NODES)
                    C[(size_t)grow * HD + gcol] = acc[i][j][r];
            }
        }
    }
}

// ---------------- el/er: one wave per (node, head), 64-lane dot ----------------
__global__ __launch_bounds__(256) void el_er_kernel(const float* __restrict__ ft,
                                                    const float* __restrict__ attn_l,
                                                    const float* __restrict__ attn_r,
                                                    float* __restrict__ el,
                                                    float* __restrict__ er) {
    int wid  = (blockIdx.x * blockDim.x + threadIdx.x) >> 6;  // (n*NH + h)
    int lane = threadIdx.x & 63;
    if (wid >= N_NODES * NH) return;
    int n = wid >> 2;
    int h = wid & 3;
    float f  = ft[(size_t)n * HD + h * DH + lane];
    float pl = f * attn_l[h * DH + lane];
    float pr = f * attn_r[h * DH + lane];
#pragma unroll
    for (int off = 32; off > 0; off >>= 1) {
        pl += __shfl_down(pl, off);
        pr += __shfl_down(pr, off);
    }
    if (lane == 0) { el[wid] = pl; er[wid] = pr; }
}

// ---------------- 3-phase parallel exclusive scan of counts -------------------
// phase 1: per-block (256 elems) sums
__global__ __launch_bounds__(256) void partial_kernel(const int* __restrict__ counts,
                                                      int* __restrict__ bsums) {
    __shared__ int red[4];
    int i = blockIdx.x * 256 + threadIdx.x;
    int c = (i < N_NODES) ? counts[i] : 0;
#pragma unroll
    for (int off = 32; off > 0; off >>= 1) c += __shfl_down(c, off);
    if ((threadIdx.x & 63) == 0) red[threadIdx.x >> 6] = c;
    __syncthreads();
    if (threadIdx.x == 0) bsums[blockIdx.x] = red[0] + red[1] + red[2] + red[3];
}

// phase 2: single tiny block scans the 196 block sums (exclusive)
__global__ __launch_bounds__(256) void bscan_kernel(const int* __restrict__ bsums,
                                                    int* __restrict__ boffs) {
    __shared__ int s[256];
    int tid = threadIdx.x;
    s[tid] = (tid < NB) ? bsums[tid] : 0;
    __syncthreads();
    for (int off = 1; off < 256; off <<= 1) {
        int x = s[tid];
        int a = (tid >= off) ? s[tid - off] : 0;
        __syncthreads();
        s[tid] = x + a;
        __syncthreads();
    }
    if (tid < NB) boffs[tid] = (tid > 0) ? s[tid - 1] : 0;
}

// phase 3: per-block exclusive scan + block offset -> offsets, cursor
__global__ __launch_bounds__(256) void scatter_scan_kernel(const int* __restrict__ counts,
                                                           const int* __restrict__ boffs,
                                                           int* __restrict__ offsets,
                                                           int* __restrict__ cursor) {
    __shared__ int s[256];
    int tid = threadIdx.x;
    int i = blockIdx.x * 256 + tid;
    s[tid] = (i < N_NODES) ? counts[i] : 0;
    __syncthreads();
    for (int off = 1; off < 256; off <<= 1) {
        int x = s[tid];
        int a = (tid >= off) ? s[tid - off] : 0;
        __syncthreads();
        s[tid] = x + a;
        __syncthreads();
    }
    int excl = (tid > 0) ? s[tid - 1] : 0;
    int o = boffs[blockIdx.x] + excl;
    if (i < N_NODES) { offsets[i] = o; cursor[i] = o; }
    if (i == 0) offsets[N_NODES] = N_EDGES;
}

// ---------------- edge scores placed directly in CSR order --------------------
__device__ __forceinline__ float lrelu_exp(float x) {
    float y = (x > 0.f) ? x : NEG * x;
    return __expf(y);
}

__global__ __launch_bounds__(256) void edge_place_kernel(const int* __restrict__ src,
                                                         const int* __restrict__ dst,
                                                         const float* __restrict__ el,
                                                         const float* __restrict__ er,
                                                         int* __restrict__ cursor,
                                                         int* __restrict__ srcs,
                                                         float* __restrict__ w4s) {
    int e = blockIdx.x * blockDim.x + threadIdx.x;
    if (e >= N_EDGES) return;
    int u = src[e], v = dst[e];
    float4 l = *(const float4*)(el + (size_t)u * NH);
    float4 r = *(const float4*)(er + (size_t)v * NH);
    float4 s;
    s.x = lrelu_exp(l.x + r.x);
    s.y = lrelu_exp(l.y + r.y);
    s.z = lrelu_exp(l.z + r.z);
    s.w = lrelu_exp(l.w + r.w);
    int pos = atomicAdd(&cursor[v], 1);
    srcs[pos] = u;
    *(float4*)(w4s + (size_t)pos * NH) = s;
}

// ---------------- aggregation: one wave per destination node ------------------
__global__ __launch_bounds__(256) void agg_kernel(const float* __restrict__ ft,
                                                  const float* __restrict__ w4s,
                                                  const int* __restrict__ srcs,
                                                  const int* __restrict__ offsets,
                                                  float* __restrict__ out) {
    int wv   = (blockIdx.x * blockDim.x + threadIdx.x) >> 6;  // node id
    int lane = threadIdx.x & 63;
    if (wv >= N_NODES) return;

    int beg = offsets[wv];
    int end = offsets[wv + 1];
    int h   = lane >> 4;

    float4 acc = make_float4(0.f, 0.f, 0.f, 0.f);
    float dsum = 0.f;

    if (beg < end) {
        int u = srcs[beg];
        for (int p = beg; p < end; p++) {
            int un  = (p + 1 < end) ? srcs[p + 1] : 0;    // prefetch next index
            float w = w4s[(size_t)p * NH + h];            // broadcast, L1-hot
            float4 f = *(const float4*)(ft + (size_t)u * HD + lane * 4);
            acc.x += w * f.x;
            acc.y += w * f.y;
            acc.z += w * f.z;
            acc.w += w * f.w;
            dsum += w;
            u = un;
        }
    }
    float inv = (dsum > 0.f) ? (1.f / dsum) : 0.f;
    acc.x *= inv; acc.y *= inv; acc.z *= inv; acc.w *= inv;
    *(float4*)(out + (size_t)wv * HD + lane * 4) = acc;
}

// ---------------- launch ----------------
extern "C" void kernel_launch(void* const* d_in, const int* in_sizes, int n_in,
                              void* d_out, int out_size, void* d_ws, size_t ws_size,
                              hipStream_t stream) {
    const float* feat   = (const float*)d_in[0];
    const float* W      = (const float*)d_in[1];
    const float* attn_l = (const float*)d_in[2];
    const float* attn_r = (const float*)d_in[3];
    const int*   src    = (const int*)d_in[4];
    const int*   dst    = (const int*)d_in[5];
    float* out = (float*)d_out;

    char* p = (char*)d_ws;
    auto alloc = [&](size_t bytes) -> char* {
        char* r = p;
        p += (bytes + 255) & ~(size_t)255;
        return r;
    };
    float*          ft      = (float*)alloc((size_t)N_NODES * HD * 4);   // 51.2 MB
    unsigned short* Wtb     = (unsigned short*)alloc((size_t)IN_F * HD * 2);
    float*          el      = (float*)alloc((size_t)N_NODES * NH * 4);
    float*          er      = (float*)alloc((size_t)N_NODES * NH * 4);
    float*          w4s     = (float*)alloc((size_t)N_EDGES * NH * 4);   // 12.8 MB
    int*            srcs    = (int*)alloc((size_t)N_EDGES * 4);          // 3.2 MB
    int*            counts  = (int*)alloc((size_t)N_NODES * 4);
    int*            offsets = (int*)alloc((size_t)(N_NODES + 1) * 4);
    int*            cursor  = (int*)alloc((size_t)N_NODES * 4);
    int*            bsums   = (int*)alloc((size_t)NB * 4);
    int*            boffs   = (int*)alloc((size_t)NB * 4);

    // 1. zero counts
    zero_kernel<<<(N_NODES + 255) / 256, 256, 0, stream>>>(counts, N_NODES);
    // 2. per-dst counts
    count_kernel<<<(N_EDGES + 255) / 256, 256, 0, stream>>>(dst, counts);
    // 3. W -> Wt bf16
    wt_kernel<<<(IN_F * HD + 255) / 256, 256, 0, stream>>>(W, Wtb);
    // 4. ft = feat @ W (bf16 MFMA)
    dim3 ggrid((N_NODES + 127) / 128, HD / 128);
    gemm_kernel<<<ggrid, 256, 0, stream>>>(feat, Wtb, ft);
    // 5. el / er
    el_er_kernel<<<(N_NODES * NH) / 4, 256, 0, stream>>>(ft, attn_l, attn_r, el, er);
    // 6. parallel 3-phase scan -> offsets, cursor
    partial_kernel<<<NB, 256, 0, stream>>>(counts, bsums);
    bscan_kernel<<<1, 256, 0, stream>>>(bsums, boffs);
    scatter_scan_kernel<<<NB, 256, 0, stream>>>(counts, boffs, offsets, cursor);
    // 7. edge scores placed in CSR order
    edge_place_kernel<<<(N_EDGES + 255) / 256, 256, 0, stream>>>(src, dst, el, er,
                                                                 cursor, srcs, w4s);
    // 8. aggregate per destination node (normalization fused)
    agg_kernel<<<(N_NODES + 3) / 4, 256, 0, stream>>>(ft, w4s, srcs, offsets, out);
}

// Round 4
// 392.851 us; speedup vs baseline: 1.8458x; 1.1082x over previous
//
#include <hip/hip_runtime.h>

#define N_NODES 50000
#define N_EDGES 800000
#define IN_F    512
#define NH      4
#define DH      64
#define HD      256   // NH*DH
#define NEG     0.2f
#define NB      ((N_NODES + 255) / 256)   // 196 scan blocks

typedef __attribute__((ext_vector_type(8))) short bf16x8;
typedef __attribute__((ext_vector_type(4))) float f32x4;

__device__ __forceinline__ unsigned short f2bf(float x) {
    unsigned u = __float_as_uint(x);
    unsigned r = (u + 0x7FFFu + ((u >> 16) & 1u)) >> 16;  // RNE
    return (unsigned short)r;
}
__device__ __forceinline__ float bf2f(unsigned short b) {
    return __uint_as_float((unsigned)b << 16);
}

// ---------------- zero int buffer ----------------
__global__ void zero_kernel(int* __restrict__ p, int n) {
    int i = blockIdx.x * blockDim.x + threadIdx.x;
    if (i < n) p[i] = 0;
}

// ---------------- per-dst edge counts ----------------
__global__ __launch_bounds__(256) void count_kernel(const int* __restrict__ dst,
                                                    int* __restrict__ counts) {
    int e = blockIdx.x * blockDim.x + threadIdx.x;
    if (e < N_EDGES) atomicAdd(&counts[dst[e]], 1);
}

// ---------------- W [512][256] fp32 -> Wt [256][512] bf16 ----------------
__global__ __launch_bounds__(256) void wt_kernel(const float* __restrict__ W,
                                                 unsigned short* __restrict__ Wtb) {
    int i = blockIdx.x * blockDim.x + threadIdx.x;  // over 512*256
    if (i >= IN_F * HD) return;
    int k = i >> 8;        // 0..511
    int n = i & 255;       // 0..255
    Wtb[(size_t)n * IN_F + k] = f2bf(W[i]);
}

// ---------------- bf16 MFMA GEMM: ftb = bf16(feat @ W) ------------------------
// 128x128 tile, BK=64, 4 waves (2x2), each wave 64x64 via 4x4 of 16x16x32 MFMA.
#define LDP 72   // padded LDS row stride in shorts (64 data + 8 pad)
__global__ __launch_bounds__(256) void gemm_kernel(const float* __restrict__ A,
                                                   const unsigned short* __restrict__ Wtb,
                                                   unsigned short* __restrict__ Cb) {
    __shared__ short A_s[128][LDP];
    __shared__ short B_s[128][LDP];

    const int tid  = threadIdx.x;
    const int lane = tid & 63;
    const int wave = tid >> 6;
    const int wr   = wave >> 1;     // 0..1 row half
    const int wc   = wave & 1;      // 0..1 col half
    const int lm   = lane & 15;
    const int quad = lane >> 4;
    const int row0 = blockIdx.x * 128;
    const int col0 = blockIdx.y * 128;

    f32x4 acc[4][4] = {};

    for (int kt = 0; kt < IN_F; kt += 64) {
        // stage A (fp32 -> bf16 in-register), 128 rows x 64 cols
#pragma unroll
        for (int it = 0; it < 4; it++) {
            int gid = it * 256 + tid;
            int row = gid >> 3;
            int c8  = (gid & 7) * 8;
            int grow = row0 + row;
            float4 v0 = make_float4(0.f, 0.f, 0.f, 0.f);
            float4 v1 = v0;
            if (grow < N_NODES) {
                const float* ap = A + (size_t)grow * IN_F + kt + c8;
                v0 = *(const float4*)(ap);
                v1 = *(const float4*)(ap + 4);
            }
            bf16x8 s;
            s[0] = (short)f2bf(v0.x); s[1] = (short)f2bf(v0.y);
            s[2] = (short)f2bf(v0.z); s[3] = (short)f2bf(v0.w);
            s[4] = (short)f2bf(v1.x); s[5] = (short)f2bf(v1.y);
            s[6] = (short)f2bf(v1.z); s[7] = (short)f2bf(v1.w);
            *(bf16x8*)(&A_s[row][c8]) = s;
        }
        // stage B (already bf16, transposed): rows are output cols
#pragma unroll
        for (int it = 0; it < 4; it++) {
            int gid = it * 256 + tid;
            int row = gid >> 3;
            int c8  = (gid & 7) * 8;
            *(bf16x8*)(&B_s[row][c8]) =
                *(const bf16x8*)(Wtb + (size_t)(col0 + row) * IN_F + kt + c8);
        }
        __syncthreads();

#pragma unroll
        for (int kk = 0; kk < 64; kk += 32) {
            bf16x8 af[4], bfr[4];
#pragma unroll
            for (int i = 0; i < 4; i++)
                af[i] = *(const bf16x8*)(&A_s[wr * 64 + i * 16 + lm][kk + quad * 8]);
#pragma unroll
            for (int j = 0; j < 4; j++)
                bfr[j] = *(const bf16x8*)(&B_s[wc * 64 + j * 16 + lm][kk + quad * 8]);
#pragma unroll
            for (int i = 0; i < 4; i++)
#pragma unroll
                for (int j = 0; j < 4; j++)
                    acc[i][j] = __builtin_amdgcn_mfma_f32_16x16x32_bf16(
                        af[i], bfr[j], acc[i][j], 0, 0, 0);
        }
        __syncthreads();
    }

    // C/D layout: col = lane&15, row = quad*4 + reg; store bf16
#pragma unroll
    for (int i = 0; i < 4; i++) {
#pragma unroll
        for (int j = 0; j < 4; j++) {
            int gcol = col0 + wc * 64 + j * 16 + lm;
#pragma unroll
            for (int r = 0; r < 4; r++) {
                int grow = row0 + wr * 64 + i * 16 + quad * 4 + r;
                if (grow < N_NODES)
                    Cb[(size_t)grow * HD + gcol] = f2bf(acc[i][j][r]);
            }
        }
    }
}

// ---------------- el/er: one wave per node, ushort4 loads ---------------------
__global__ __launch_bounds__(256) void el_er_kernel(const unsigned short* __restrict__ ftb,
                                                    const float* __restrict__ attn_l,
                                                    const float* __restrict__ attn_r,
                                                    float* __restrict__ el,
                                                    float* __restrict__ er) {
    int n    = (blockIdx.x * blockDim.x + threadIdx.x) >> 6;
    int lane = threadIdx.x & 63;
    if (n >= N_NODES) return;
    int h = lane >> 4;              // head owning this lane's 4 cols
    int c = lane * 4;               // absolute col (h*64 + (lane&15)*4)

    ushort4 fv = *(const ushort4*)(ftb + (size_t)n * HD + c);
    float4 al = *(const float4*)(attn_l + c);
    float4 ar = *(const float4*)(attn_r + c);
    float f0 = bf2f(fv.x), f1 = bf2f(fv.y), f2 = bf2f(fv.z), f3 = bf2f(fv.w);
    float pl = f0 * al.x + f1 * al.y + f2 * al.z + f3 * al.w;
    float pr = f0 * ar.x + f1 * ar.y + f2 * ar.z + f3 * ar.w;
#pragma unroll
    for (int off = 8; off > 0; off >>= 1) {   // reduce within each 16-lane group
        pl += __shfl_down(pl, off);
        pr += __shfl_down(pr, off);
    }
    if ((lane & 15) == 0) {
        el[(size_t)n * NH + h] = pl;
        er[(size_t)n * NH + h] = pr;
    }
}

// ---------------- 3-phase parallel exclusive scan of counts -------------------
__global__ __launch_bounds__(256) void partial_kernel(const int* __restrict__ counts,
                                                      int* __restrict__ bsums) {
    __shared__ int red[4];
    int i = blockIdx.x * 256 + threadIdx.x;
    int c = (i < N_NODES) ? counts[i] : 0;
#pragma unroll
    for (int off = 32; off > 0; off >>= 1) c += __shfl_down(c, off);
    if ((threadIdx.x & 63) == 0) red[threadIdx.x >> 6] = c;
    __syncthreads();
    if (threadIdx.x == 0) bsums[blockIdx.x] = red[0] + red[1] + red[2] + red[3];
}

__global__ __launch_bounds__(256) void bscan_kernel(const int* __restrict__ bsums,
                                                    int* __restrict__ boffs) {
    __shared__ int s[256];
    int tid = threadIdx.x;
    s[tid] = (tid < NB) ? bsums[tid] : 0;
    __syncthreads();
    for (int off = 1; off < 256; off <<= 1) {
        int x = s[tid];
        int a = (tid >= off) ? s[tid - off] : 0;
        __syncthreads();
        s[tid] = x + a;
        __syncthreads();
    }
    if (tid < NB) boffs[tid] = (tid > 0) ? s[tid - 1] : 0;
}

__global__ __launch_bounds__(256) void scatter_scan_kernel(const int* __restrict__ counts,
                                                           const int* __restrict__ boffs,
                                                           int* __restrict__ offsets,
                                                           int* __restrict__ cursor) {
    __shared__ int s[256];
    int tid = threadIdx.x;
    int i = blockIdx.x * 256 + tid;
    s[tid] = (i < N_NODES) ? counts[i] : 0;
    __syncthreads();
    for (int off = 1; off < 256; off <<= 1) {
        int x = s[tid];
        int a = (tid >= off) ? s[tid - off] : 0;
        __syncthreads();
        s[tid] = x + a;
        __syncthreads();
    }
    int excl = (tid > 0) ? s[tid - 1] : 0;
    int o = boffs[blockIdx.x] + excl;
    if (i < N_NODES) { offsets[i] = o; cursor[i] = o; }
    if (i == 0) offsets[N_NODES] = N_EDGES;
}

// ---------------- edge scores placed directly in CSR order --------------------
__device__ __forceinline__ float lrelu_exp(float x) {
    float y = (x > 0.f) ? x : NEG * x;
    return __expf(y);
}

__global__ __launch_bounds__(256) void edge_place_kernel(const int* __restrict__ src,
                                                         const int* __restrict__ dst,
                                                         const float* __restrict__ el,
                                                         const float* __restrict__ er,
                                                         int* __restrict__ cursor,
                                                         int* __restrict__ srcs,
                                                         float* __restrict__ w4s) {
    int e = blockIdx.x * blockDim.x + threadIdx.x;
    if (e >= N_EDGES) return;
    int u = src[e], v = dst[e];
    float4 l = *(const float4*)(el + (size_t)u * NH);
    float4 r = *(const float4*)(er + (size_t)v * NH);
    float4 s;
    s.x = lrelu_exp(l.x + r.x);
    s.y = lrelu_exp(l.y + r.y);
    s.z = lrelu_exp(l.z + r.z);
    s.w = lrelu_exp(l.w + r.w);
    int pos = atomicAdd(&cursor[v], 1);
    srcs[pos] = u;
    *(float4*)(w4s + (size_t)pos * NH) = s;
}

// ---------------- aggregation: one wave per dst node, bf16 gathers ------------
__global__ __launch_bounds__(256) void agg_kernel(const unsigned short* __restrict__ ftb,
                                                  const float* __restrict__ w4s,
                                                  const int* __restrict__ srcs,
                                                  const int* __restrict__ offsets,
                                                  float* __restrict__ out) {
    int wv   = (blockIdx.x * blockDim.x + threadIdx.x) >> 6;  // node id
    int lane = threadIdx.x & 63;
    if (wv >= N_NODES) return;

    int beg = offsets[wv];
    int end = offsets[wv + 1];
    int h   = lane >> 4;

    float4 acc = make_float4(0.f, 0.f, 0.f, 0.f);
    float dsum = 0.f;

    if (beg < end) {
        int u = srcs[beg];
        for (int p = beg; p < end; p++) {
            int un  = (p + 1 < end) ? srcs[p + 1] : 0;    // prefetch next index
            float w = w4s[(size_t)p * NH + h];            // broadcast, L1-hot
            ushort4 f = *(const ushort4*)(ftb + (size_t)u * HD + lane * 4);
            acc.x += w * bf2f(f.x);
            acc.y += w * bf2f(f.y);
            acc.z += w * bf2f(f.z);
            acc.w += w * bf2f(f.w);
            dsum += w;
            u = un;
        }
    }
    float inv = (dsum > 0.f) ? (1.f / dsum) : 0.f;
    acc.x *= inv; acc.y *= inv; acc.z *= inv; acc.w *= inv;
    *(float4*)(out + (size_t)wv * HD + lane * 4) = acc;
}

// ---------------- launch ----------------
extern "C" void kernel_launch(void* const* d_in, const int* in_sizes, int n_in,
                              void* d_out, int out_size, void* d_ws, size_t ws_size,
                              hipStream_t stream) {
    const float* feat   = (const float*)d_in[0];
    const float* W      = (const float*)d_in[1];
    const float* attn_l = (const float*)d_in[2];
    const float* attn_r = (const float*)d_in[3];
    const int*   src    = (const int*)d_in[4];
    const int*   dst    = (const int*)d_in[5];
    float* out = (float*)d_out;

    char* p = (char*)d_ws;
    auto alloc = [&](size_t bytes) -> char* {
        char* r = p;
        p += (bytes + 255) & ~(size_t)255;
        return r;
    };
    unsigned short* ftb     = (unsigned short*)alloc((size_t)N_NODES * HD * 2); // 25.6 MB
    unsigned short* Wtb     = (unsigned short*)alloc((size_t)IN_F * HD * 2);
    float*          el      = (float*)alloc((size_t)N_NODES * NH * 4);
    float*          er      = (float*)alloc((size_t)N_NODES * NH * 4);
    float*          w4s     = (float*)alloc((size_t)N_EDGES * NH * 4);   // 12.8 MB
    int*            srcs    = (int*)alloc((size_t)N_EDGES * 4);          // 3.2 MB
    int*            counts  = (int*)alloc((size_t)N_NODES * 4);
    int*            offsets = (int*)alloc((size_t)(N_NODES + 1) * 4);
    int*            cursor  = (int*)alloc((size_t)N_NODES * 4);
    int*            bsums   = (int*)alloc((size_t)NB * 4);
    int*            boffs   = (int*)alloc((size_t)NB * 4);

    // 1. zero counts
    zero_kernel<<<(N_NODES + 255) / 256, 256, 0, stream>>>(counts, N_NODES);
    // 2. per-dst counts
    count_kernel<<<(N_EDGES + 255) / 256, 256, 0, stream>>>(dst, counts);
    // 3. W -> Wt bf16
    wt_kernel<<<(IN_F * HD + 255) / 256, 256, 0, stream>>>(W, Wtb);
    // 4. ftb = bf16(feat @ W) (bf16 MFMA)
    dim3 ggrid((N_NODES + 127) / 128, HD / 128);
    gemm_kernel<<<ggrid, 256, 0, stream>>>(feat, Wtb, ftb);
    // 5. el / er (one wave per node)
    el_er_kernel<<<(N_NODES + 3) / 4, 256, 0, stream>>>(ftb, attn_l, attn_r, el, er);
    // 6. parallel 3-phase scan -> offsets, cursor
    partial_kernel<<<NB, 256, 0, stream>>>(counts, bsums);
    bscan_kernel<<<1, 256, 0, stream>>>(bsums, boffs);
    scatter_scan_kernel<<<NB, 256, 0, stream>>>(counts, boffs, offsets, cursor);
    // 7. edge scores placed in CSR order
    edge_place_kernel<<<(N_EDGES + 255) / 256, 256, 0, stream>>>(src, dst, el, er,
                                                                 cursor, srcs, w4s);
    // 8. aggregate per destination node (normalization fused)
    agg_kernel<<<(N_NODES + 3) / 4, 256, 0, stream>>>(ftb, w4s, srcs, offsets, out);
}

// Round 5
// 357.105 us; speedup vs baseline: 2.0305x; 1.1001x over previous
//
#include <hip/hip_runtime.h>

#define N_NODES 50000
#define N_EDGES 800000
#define IN_F    512
#define NH      4
#define DH      64
#define HD      256   // NH*DH
#define NEG     0.2f
#define NB      ((N_NODES + 255) / 256)   // 196 scan blocks

typedef __attribute__((ext_vector_type(8))) short bf16x8;
typedef __attribute__((ext_vector_type(4))) float f32x4;

__device__ __forceinline__ unsigned short f2bf(float x) {
    unsigned u = __float_as_uint(x);
    unsigned r = (u + 0x7FFFu + ((u >> 16) & 1u)) >> 16;  // RNE
    return (unsigned short)r;
}
__device__ __forceinline__ float bf2f(unsigned short b) {
    return __uint_as_float((unsigned)b << 16);
}

// ---------------- zero int buffer ----------------
__global__ void zero_kernel(int* __restrict__ p, int n) {
    int i = blockIdx.x * blockDim.x + threadIdx.x;
    if (i < n) p[i] = 0;
}

// ---------------- per-dst edge counts ----------------
__global__ __launch_bounds__(256) void count_kernel(const int* __restrict__ dst,
                                                    int* __restrict__ counts) {
    int e = blockIdx.x * blockDim.x + threadIdx.x;
    if (e < N_EDGES) atomicAdd(&counts[dst[e]], 1);
}

// ---------------- W [512][256] fp32 -> Wt [256][512] bf16 ----------------
__global__ __launch_bounds__(256) void wt_kernel(const float* __restrict__ W,
                                                 unsigned short* __restrict__ Wtb) {
    int i = blockIdx.x * blockDim.x + threadIdx.x;  // over 512*256
    if (i >= IN_F * HD) return;
    int k = i >> 8;        // 0..511
    int n = i & 255;       // 0..255
    Wtb[(size_t)n * IN_F + k] = f2bf(W[i]);
}

// ---------------- bf16 MFMA GEMM: ftb = bf16(feat @ W) ------------------------
// 128x128 tile, BK=64, 4 waves (2x2), each wave 64x64 via 4x4 of 16x16x32 MFMA.
#define LDP 72   // padded LDS row stride in shorts (64 data + 8 pad)
__global__ __launch_bounds__(256) void gemm_kernel(const float* __restrict__ A,
                                                   const unsigned short* __restrict__ Wtb,
                                                   unsigned short* __restrict__ Cb) {
    __shared__ short A_s[128][LDP];
    __shared__ short B_s[128][LDP];

    const int tid  = threadIdx.x;
    const int lane = tid & 63;
    const int wave = tid >> 6;
    const int wr   = wave >> 1;     // 0..1 row half
    const int wc   = wave & 1;      // 0..1 col half
    const int lm   = lane & 15;
    const int quad = lane >> 4;
    const int row0 = blockIdx.x * 128;
    const int col0 = blockIdx.y * 128;

    f32x4 acc[4][4] = {};

    for (int kt = 0; kt < IN_F; kt += 64) {
        // stage A (fp32 -> bf16 in-register), 128 rows x 64 cols
#pragma unroll
        for (int it = 0; it < 4; it++) {
            int gid = it * 256 + tid;
            int row = gid >> 3;
            int c8  = (gid & 7) * 8;
            int grow = row0 + row;
            float4 v0 = make_float4(0.f, 0.f, 0.f, 0.f);
            float4 v1 = v0;
            if (grow < N_NODES) {
                const float* ap = A + (size_t)grow * IN_F + kt + c8;
                v0 = *(const float4*)(ap);
                v1 = *(const float4*)(ap + 4);
            }
            bf16x8 s;
            s[0] = (short)f2bf(v0.x); s[1] = (short)f2bf(v0.y);
            s[2] = (short)f2bf(v0.z); s[3] = (short)f2bf(v0.w);
            s[4] = (short)f2bf(v1.x); s[5] = (short)f2bf(v1.y);
            s[6] = (short)f2bf(v1.z); s[7] = (short)f2bf(v1.w);
            *(bf16x8*)(&A_s[row][c8]) = s;
        }
        // stage B (already bf16, transposed): rows are output cols
#pragma unroll
        for (int it = 0; it < 4; it++) {
            int gid = it * 256 + tid;
            int row = gid >> 3;
            int c8  = (gid & 7) * 8;
            *(bf16x8*)(&B_s[row][c8]) =
                *(const bf16x8*)(Wtb + (size_t)(col0 + row) * IN_F + kt + c8);
        }
        __syncthreads();

#pragma unroll
        for (int kk = 0; kk < 64; kk += 32) {
            bf16x8 af[4], bfr[4];
#pragma unroll
            for (int i = 0; i < 4; i++)
                af[i] = *(const bf16x8*)(&A_s[wr * 64 + i * 16 + lm][kk + quad * 8]);
#pragma unroll
            for (int j = 0; j < 4; j++)
                bfr[j] = *(const bf16x8*)(&B_s[wc * 64 + j * 16 + lm][kk + quad * 8]);
#pragma unroll
            for (int i = 0; i < 4; i++)
#pragma unroll
                for (int j = 0; j < 4; j++)
                    acc[i][j] = __builtin_amdgcn_mfma_f32_16x16x32_bf16(
                        af[i], bfr[j], acc[i][j], 0, 0, 0);
        }
        __syncthreads();
    }

    // C/D layout: col = lane&15, row = quad*4 + reg; store bf16
#pragma unroll
    for (int i = 0; i < 4; i++) {
#pragma unroll
        for (int j = 0; j < 4; j++) {
            int gcol = col0 + wc * 64 + j * 16 + lm;
#pragma unroll
            for (int r = 0; r < 4; r++) {
                int grow = row0 + wr * 64 + i * 16 + quad * 4 + r;
                if (grow < N_NODES)
                    Cb[(size_t)grow * HD + gcol] = f2bf(acc[i][j][r]);
            }
        }
    }
}

// ---------------- el/er: one wave per node, ushort4 loads ---------------------
__global__ __launch_bounds__(256) void el_er_kernel(const unsigned short* __restrict__ ftb,
                                                    const float* __restrict__ attn_l,
                                                    const float* __restrict__ attn_r,
                                                    float* __restrict__ el,
                                                    float* __restrict__ er) {
    int n    = (blockIdx.x * blockDim.x + threadIdx.x) >> 6;
    int lane = threadIdx.x & 63;
    if (n >= N_NODES) return;
    int h = lane >> 4;              // head owning this lane's 4 cols
    int c = lane * 4;               // absolute col (h*64 + (lane&15)*4)

    ushort4 fv = *(const ushort4*)(ftb + (size_t)n * HD + c);
    float4 al = *(const float4*)(attn_l + c);
    float4 ar = *(const float4*)(attn_r + c);
    float f0 = bf2f(fv.x), f1 = bf2f(fv.y), f2 = bf2f(fv.z), f3 = bf2f(fv.w);
    float pl = f0 * al.x + f1 * al.y + f2 * al.z + f3 * al.w;
    float pr = f0 * ar.x + f1 * ar.y + f2 * ar.z + f3 * ar.w;
#pragma unroll
    for (int off = 8; off > 0; off >>= 1) {   // reduce within each 16-lane group
        pl += __shfl_down(pl, off);
        pr += __shfl_down(pr, off);
    }
    if ((lane & 15) == 0) {
        el[(size_t)n * NH + h] = pl;
        er[(size_t)n * NH + h] = pr;
    }
}

// ---------------- 3-phase parallel exclusive scan of counts -------------------
__global__ __launch_bounds__(256) void partial_kernel(const int* __restrict__ counts,
                                                      int* __restrict__ bsums) {
    __shared__ int red[4];
    int i = blockIdx.x * 256 + threadIdx.x;
    int c = (i < N_NODES) ? counts[i] : 0;
#pragma unroll
    for (int off = 32; off > 0; off >>= 1) c += __shfl_down(c, off);
    if ((threadIdx.x & 63) == 0) red[threadIdx.x >> 6] = c;
    __syncthreads();
    if (threadIdx.x == 0) bsums[blockIdx.x] = red[0] + red[1] + red[2] + red[3];
}

__global__ __launch_bounds__(256) void bscan_kernel(const int* __restrict__ bsums,
                                                    int* __restrict__ boffs) {
    __shared__ int s[256];
    int tid = threadIdx.x;
    s[tid] = (tid < NB) ? bsums[tid] : 0;
    __syncthreads();
    for (int off = 1; off < 256; off <<= 1) {
        int x = s[tid];
        int a = (tid >= off) ? s[tid - off] : 0;
        __syncthreads();
        s[tid] = x + a;
        __syncthreads();
    }
    if (tid < NB) boffs[tid] = (tid > 0) ? s[tid - 1] : 0;
}

__global__ __launch_bounds__(256) void scatter_scan_kernel(const int* __restrict__ counts,
                                                           const int* __restrict__ boffs,
                                                           int* __restrict__ offsets,
                                                           int* __restrict__ cursor) {
    __shared__ int s[256];
    int tid = threadIdx.x;
    int i = blockIdx.x * 256 + tid;
    s[tid] = (i < N_NODES) ? counts[i] : 0;
    __syncthreads();
    for (int off = 1; off < 256; off <<= 1) {
        int x = s[tid];
        int a = (tid >= off) ? s[tid - off] : 0;
        __syncthreads();
        s[tid] = x + a;
        __syncthreads();
    }
    int excl = (tid > 0) ? s[tid - 1] : 0;
    int o = boffs[blockIdx.x] + excl;
    if (i < N_NODES) { offsets[i] = o; cursor[i] = o; }
    if (i == 0) offsets[N_NODES] = N_EDGES;
}

// ---------------- edge scores placed directly in CSR order --------------------
__device__ __forceinline__ float lrelu_exp(float x) {
    float y = (x > 0.f) ? x : NEG * x;
    return __expf(y);
}

__global__ __launch_bounds__(256) void edge_place_kernel(const int* __restrict__ src,
                                                         const int* __restrict__ dst,
                                                         const float* __restrict__ el,
                                                         const float* __restrict__ er,
                                                         int* __restrict__ cursor,
                                                         int* __restrict__ srcs,
                                                         float* __restrict__ w4s) {
    int e = blockIdx.x * blockDim.x + threadIdx.x;
    if (e >= N_EDGES) return;
    int u = src[e], v = dst[e];
    float4 l = *(const float4*)(el + (size_t)u * NH);
    float4 r = *(const float4*)(er + (size_t)v * NH);
    float4 s;
    s.x = lrelu_exp(l.x + r.x);
    s.y = lrelu_exp(l.y + r.y);
    s.z = lrelu_exp(l.z + r.z);
    s.w = lrelu_exp(l.w + r.w);
    int pos = atomicAdd(&cursor[v], 1);
    srcs[pos] = u;
    *(float4*)(w4s + (size_t)pos * NH) = s;
}

// ---------------- aggregation: one wave per dst, 4-edge software pipeline -----
__global__ __launch_bounds__(256) void agg_kernel(const unsigned short* __restrict__ ftb,
                                                  const float* __restrict__ w4s,
                                                  const int* __restrict__ srcs,
                                                  const int* __restrict__ offsets,
                                                  float* __restrict__ out) {
    int wv   = (blockIdx.x * blockDim.x + threadIdx.x) >> 6;  // node id
    int lane = threadIdx.x & 63;
    if (wv >= N_NODES) return;

    const int beg = offsets[wv];
    const int end = offsets[wv + 1];
    const int h   = lane >> 4;
    const size_t foff = (size_t)lane * 4;

    float4 acc = make_float4(0.f, 0.f, 0.f, 0.f);
    float dsum = 0.f;

    const int n4 = (end - beg) >> 2;   // full 4-edge blocks
    int u0, u1, u2, u3;
    if (n4 > 0) {
        const int* sp = srcs + beg;
        u0 = sp[0]; u1 = sp[1]; u2 = sp[2]; u3 = sp[3];
        for (int b = 0; b < n4; b++) {
            const int base = beg + b * 4;
            // preload next block's indices (breaks the idx->gather chain)
            int v0 = 0, v1 = 0, v2 = 0, v3 = 0;
            if (b + 1 < n4) {
                const int* np = srcs + base + 4;
                v0 = np[0]; v1 = np[1]; v2 = np[2]; v3 = np[3];
            }
            // 4 independent 512B gathers in flight
            ushort4 f0 = *(const ushort4*)(ftb + (size_t)u0 * HD + foff);
            ushort4 f1 = *(const ushort4*)(ftb + (size_t)u1 * HD + foff);
            ushort4 f2 = *(const ushort4*)(ftb + (size_t)u2 * HD + foff);
            ushort4 f3 = *(const ushort4*)(ftb + (size_t)u3 * HD + foff);
            float w0 = w4s[(size_t)(base + 0) * NH + h];
            float w1 = w4s[(size_t)(base + 1) * NH + h];
            float w2 = w4s[(size_t)(base + 2) * NH + h];
            float w3 = w4s[(size_t)(base + 3) * NH + h];
            acc.x += w0 * bf2f(f0.x) + w1 * bf2f(f1.x) + w2 * bf2f(f2.x) + w3 * bf2f(f3.x);
            acc.y += w0 * bf2f(f0.y) + w1 * bf2f(f1.y) + w2 * bf2f(f2.y) + w3 * bf2f(f3.y);
            acc.z += w0 * bf2f(f0.z) + w1 * bf2f(f1.z) + w2 * bf2f(f2.z) + w3 * bf2f(f3.z);
            acc.w += w0 * bf2f(f0.w) + w1 * bf2f(f1.w) + w2 * bf2f(f2.w) + w3 * bf2f(f3.w);
            dsum += (w0 + w1) + (w2 + w3);
            u0 = v0; u1 = v1; u2 = v2; u3 = v3;
        }
    }
    // tail (0..3 edges)
    for (int p = beg + n4 * 4; p < end; p++) {
        int u = srcs[p];
        float w = w4s[(size_t)p * NH + h];
        ushort4 f = *(const ushort4*)(ftb + (size_t)u * HD + foff);
        acc.x += w * bf2f(f.x);
        acc.y += w * bf2f(f.y);
        acc.z += w * bf2f(f.z);
        acc.w += w * bf2f(f.w);
        dsum += w;
    }

    float inv = (dsum > 0.f) ? (1.f / dsum) : 0.f;
    acc.x *= inv; acc.y *= inv; acc.z *= inv; acc.w *= inv;
    *(float4*)(out + (size_t)wv * HD + foff) = acc;
}

// ---------------- launch ----------------
extern "C" void kernel_launch(void* const* d_in, const int* in_sizes, int n_in,
                              void* d_out, int out_size, void* d_ws, size_t ws_size,
                              hipStream_t stream) {
    const float* feat   = (const float*)d_in[0];
    const float* W      = (const float*)d_in[1];
    const float* attn_l = (const float*)d_in[2];
    const float* attn_r = (const float*)d_in[3];
    const int*   src    = (const int*)d_in[4];
    const int*   dst    = (const int*)d_in[5];
    float* out = (float*)d_out;

    char* p = (char*)d_ws;
    auto alloc = [&](size_t bytes) -> char* {
        char* r = p;
        p += (bytes + 255) & ~(size_t)255;
        return r;
    };
    unsigned short* ftb     = (unsigned short*)alloc((size_t)N_NODES * HD * 2); // 25.6 MB
    unsigned short* Wtb     = (unsigned short*)alloc((size_t)IN_F * HD * 2);
    float*          el      = (float*)alloc((size_t)N_NODES * NH * 4);
    float*          er      = (float*)alloc((size_t)N_NODES * NH * 4);
    float*          w4s     = (float*)alloc((size_t)N_EDGES * NH * 4);   // 12.8 MB
    int*            srcs    = (int*)alloc((size_t)N_EDGES * 4);          // 3.2 MB
    int*            counts  = (int*)alloc((size_t)N_NODES * 4);
    int*            offsets = (int*)alloc((size_t)(N_NODES + 1) * 4);
    int*            cursor  = (int*)alloc((size_t)N_NODES * 4);
    int*            bsums   = (int*)alloc((size_t)NB * 4);
    int*            boffs   = (int*)alloc((size_t)NB * 4);

    // 1. zero counts
    zero_kernel<<<(N_NODES + 255) / 256, 256, 0, stream>>>(counts, N_NODES);
    // 2. per-dst counts
    count_kernel<<<(N_EDGES + 255) / 256, 256, 0, stream>>>(dst, counts);
    // 3. W -> Wt bf16
    wt_kernel<<<(IN_F * HD + 255) / 256, 256, 0, stream>>>(W, Wtb);
    // 4. ftb = bf16(feat @ W) (bf16 MFMA)
    dim3 ggrid((N_NODES + 127) / 128, HD / 128);
    gemm_kernel<<<ggrid, 256, 0, stream>>>(feat, Wtb, ftb);
    // 5. el / er (one wave per node)
    el_er_kernel<<<(N_NODES + 3) / 4, 256, 0, stream>>>(ftb, attn_l, attn_r, el, er);
    // 6. parallel 3-phase scan -> offsets, cursor
    partial_kernel<<<NB, 256, 0, stream>>>(counts, bsums);
    bscan_kernel<<<1, 256, 0, stream>>>(bsums, boffs);
    scatter_scan_kernel<<<NB, 256, 0, stream>>>(counts, boffs, offsets, cursor);
    // 7. edge scores placed in CSR order
    edge_place_kernel<<<(N_EDGES + 255) / 256, 256, 0, stream>>>(src, dst, el, er,
                                                                 cursor, srcs, w4s);
    // 8. aggregate per destination node (normalization fused)
    agg_kernel<<<(N_NODES + 3) / 4, 256, 0, stream>>>(ftb, w4s, srcs, offsets, out);
}

// Round 6
// 349.475 us; speedup vs baseline: 2.0749x; 1.0218x over previous
//
#include <hip/hip_runtime.h>

#define N_NODES 50000
#define N_EDGES 800000
#define IN_F    512
#define NH      4
#define DH      64
#define HD      256   // NH*DH
#define NEG     0.2f
#define NB      ((N_NODES + 255) / 256)   // 196 scan blocks

typedef __attribute__((ext_vector_type(8))) short bf16x8;
typedef __attribute__((ext_vector_type(4))) float f32x4;

__device__ __forceinline__ unsigned short f2bf(float x) {
    unsigned u = __float_as_uint(x);
    unsigned r = (u + 0x7FFFu + ((u >> 16) & 1u)) >> 16;  // RNE
    return (unsigned short)r;
}
__device__ __forceinline__ float bf2f(unsigned short b) {
    return __uint_as_float((unsigned)b << 16);
}

// ---------------- zero int buffer ----------------
__global__ void zero_kernel(int* __restrict__ p, int n) {
    int i = blockIdx.x * blockDim.x + threadIdx.x;
    if (i < n) p[i] = 0;
}

// ---------------- per-dst edge counts ----------------
__global__ __launch_bounds__(256) void count_kernel(const int* __restrict__ dst,
                                                    int* __restrict__ counts) {
    int e = blockIdx.x * blockDim.x + threadIdx.x;
    if (e < N_EDGES) atomicAdd(&counts[dst[e]], 1);
}

// ---------------- W [512][256] fp32 -> Wt [256][512] bf16 ----------------
__global__ __launch_bounds__(256) void wt_kernel(const float* __restrict__ W,
                                                 unsigned short* __restrict__ Wtb) {
    int i = blockIdx.x * blockDim.x + threadIdx.x;  // over 512*256
    if (i >= IN_F * HD) return;
    int k = i >> 8;        // 0..511
    int n = i & 255;       // 0..255
    Wtb[(size_t)n * IN_F + k] = f2bf(W[i]);
}

// ---------------- bf16 MFMA GEMM: ftb = bf16(feat @ W) ------------------------
// 64x128 tile, BK=64, 4 waves (2x2, each 32x64), register-prefetch pipeline:
// tile k+1's global loads issue right after the store barrier, overlapping
// compute of tile k (m33 pattern). 1564 blocks -> ~6 blocks/CU by grid.
#define LDPA 72   // padded LDS row stride in shorts
#define LDPB 72
__global__ __launch_bounds__(256) void gemm_kernel(const float* __restrict__ A,
                                                   const unsigned short* __restrict__ Wtb,
                                                   unsigned short* __restrict__ Cb) {
    __shared__ short A_s[64][LDPA];    // 9.2 KB
    __shared__ short B_s[128][LDPB];   // 18.4 KB

    const int tid  = threadIdx.x;
    const int lane = tid & 63;
    const int wave = tid >> 6;
    const int wr   = wave >> 1;     // row half (each 32 rows)
    const int wc   = wave & 1;      // col half (each 64 cols)
    const int lm   = lane & 15;
    const int quad = lane >> 4;
    const int row0 = blockIdx.x * 64;
    const int col0 = blockIdx.y * 128;

    // staging: unit = 8 contiguous elems; A 64x64 fp32 (2 units/thr),
    // B 128x64 bf16 (4 units/thr)
    const int srow = tid >> 3;          // 0..31
    const int sc8  = (tid & 7) * 8;

    f32x4 acc[2][4] = {};
    float4 pa[4];
    bf16x8 pb[4];

#define LOAD_TILES(KT)                                                         \
    {                                                                          \
        int g0 = row0 + srow;                                                  \
        if (g0 < N_NODES) {                                                    \
            const float* ap = A + (size_t)g0 * IN_F + (KT) + sc8;              \
            pa[0] = *(const float4*)ap; pa[1] = *(const float4*)(ap + 4);      \
        } else { pa[0] = pa[1] = make_float4(0.f, 0.f, 0.f, 0.f); }            \
        int g1 = row0 + 32 + srow;                                             \
        if (g1 < N_NODES) {                                                    \
            const float* ap = A + (size_t)g1 * IN_F + (KT) + sc8;              \
            pa[2] = *(const float4*)ap; pa[3] = *(const float4*)(ap + 4);      \
        } else { pa[2] = pa[3] = make_float4(0.f, 0.f, 0.f, 0.f); }            \
        _Pragma("unroll")                                                      \
        for (int it = 0; it < 4; it++) {                                       \
            int brow = it * 32 + srow;                                         \
            pb[it] = *(const bf16x8*)(Wtb + (size_t)(col0 + brow) * IN_F +     \
                                      (KT) + sc8);                             \
        }                                                                      \
    }

    LOAD_TILES(0);

    for (int kt = 0; kt < IN_F; kt += 64) {
        // convert + store current prefetched tile to LDS (vmcnt wait lands here)
        {
            bf16x8 s;
            s[0] = (short)f2bf(pa[0].x); s[1] = (short)f2bf(pa[0].y);
            s[2] = (short)f2bf(pa[0].z); s[3] = (short)f2bf(pa[0].w);
            s[4] = (short)f2bf(pa[1].x); s[5] = (short)f2bf(pa[1].y);
            s[6] = (short)f2bf(pa[1].z); s[7] = (short)f2bf(pa[1].w);
            *(bf16x8*)(&A_s[srow][sc8]) = s;
            s[0] = (short)f2bf(pa[2].x); s[1] = (short)f2bf(pa[2].y);
            s[2] = (short)f2bf(pa[2].z); s[3] = (short)f2bf(pa[2].w);
            s[4] = (short)f2bf(pa[3].x); s[5] = (short)f2bf(pa[3].y);
            s[6] = (short)f2bf(pa[3].z); s[7] = (short)f2bf(pa[3].w);
            *(bf16x8*)(&A_s[32 + srow][sc8]) = s;
#pragma unroll
            for (int it = 0; it < 4; it++)
                *(bf16x8*)(&B_s[it * 32 + srow][sc8]) = pb[it];
        }
        __syncthreads();

        // issue next tile's global loads (overlap with compute below)
        if (kt + 64 < IN_F) LOAD_TILES(kt + 64);

        // compute current tile from LDS
#pragma unroll
        for (int kk = 0; kk < 64; kk += 32) {
            bf16x8 af[2], bfr[4];
#pragma unroll
            for (int i = 0; i < 2; i++)
                af[i] = *(const bf16x8*)(&A_s[wr * 32 + i * 16 + lm][kk + quad * 8]);
#pragma unroll
            for (int j = 0; j < 4; j++)
                bfr[j] = *(const bf16x8*)(&B_s[wc * 64 + j * 16 + lm][kk + quad * 8]);
#pragma unroll
            for (int i = 0; i < 2; i++)
#pragma unroll
                for (int j = 0; j < 4; j++)
                    acc[i][j] = __builtin_amdgcn_mfma_f32_16x16x32_bf16(
                        af[i], bfr[j], acc[i][j], 0, 0, 0);
        }
        __syncthreads();   // protect LDS before next iteration's store
    }
#undef LOAD_TILES

    // C/D layout: col = lane&15, row = quad*4 + reg; store bf16
#pragma unroll
    for (int i = 0; i < 2; i++) {
#pragma unroll
        for (int j = 0; j < 4; j++) {
            int gcol = col0 + wc * 64 + j * 16 + lm;
#pragma unroll
            for (int r = 0; r < 4; r++) {
                int grow = row0 + wr * 32 + i * 16 + quad * 4 + r;
                if (grow < N_NODES)
                    Cb[(size_t)grow * HD + gcol] = f2bf(acc[i][j][r]);
            }
        }
    }
}

// ---------------- el/er: one wave per node, ushort4 loads ---------------------
__global__ __launch_bounds__(256) void el_er_kernel(const unsigned short* __restrict__ ftb,
                                                    const float* __restrict__ attn_l,
                                                    const float* __restrict__ attn_r,
                                                    float* __restrict__ el,
                                                    float* __restrict__ er) {
    int n    = (blockIdx.x * blockDim.x + threadIdx.x) >> 6;
    int lane = threadIdx.x & 63;
    if (n >= N_NODES) return;
    int h = lane >> 4;              // head owning this lane's 4 cols
    int c = lane * 4;               // absolute col (h*64 + (lane&15)*4)

    ushort4 fv = *(const ushort4*)(ftb + (size_t)n * HD + c);
    float4 al = *(const float4*)(attn_l + c);
    float4 ar = *(const float4*)(attn_r + c);
    float f0 = bf2f(fv.x), f1 = bf2f(fv.y), f2 = bf2f(fv.z), f3 = bf2f(fv.w);
    float pl = f0 * al.x + f1 * al.y + f2 * al.z + f3 * al.w;
    float pr = f0 * ar.x + f1 * ar.y + f2 * ar.z + f3 * ar.w;
#pragma unroll
    for (int off = 8; off > 0; off >>= 1) {   // reduce within each 16-lane group
        pl += __shfl_down(pl, off);
        pr += __shfl_down(pr, off);
    }
    if ((lane & 15) == 0) {
        el[(size_t)n * NH + h] = pl;
        er[(size_t)n * NH + h] = pr;
    }
}

// ---------------- 3-phase parallel exclusive scan of counts -------------------
__global__ __launch_bounds__(256) void partial_kernel(const int* __restrict__ counts,
                                                      int* __restrict__ bsums) {
    __shared__ int red[4];
    int i = blockIdx.x * 256 + threadIdx.x;
    int c = (i < N_NODES) ? counts[i] : 0;
#pragma unroll
    for (int off = 32; off > 0; off >>= 1) c += __shfl_down(c, off);
    if ((threadIdx.x & 63) == 0) red[threadIdx.x >> 6] = c;
    __syncthreads();
    if (threadIdx.x == 0) bsums[blockIdx.x] = red[0] + red[1] + red[2] + red[3];
}

__global__ __launch_bounds__(256) void bscan_kernel(const int* __restrict__ bsums,
                                                    int* __restrict__ boffs) {
    __shared__ int s[256];
    int tid = threadIdx.x;
    s[tid] = (tid < NB) ? bsums[tid] : 0;
    __syncthreads();
    for (int off = 1; off < 256; off <<= 1) {
        int x = s[tid];
        int a = (tid >= off) ? s[tid - off] : 0;
        __syncthreads();
        s[tid] = x + a;
        __syncthreads();
    }
    if (tid < NB) boffs[tid] = (tid > 0) ? s[tid - 1] : 0;
}

__global__ __launch_bounds__(256) void scatter_scan_kernel(const int* __restrict__ counts,
                                                           const int* __restrict__ boffs,
                                                           int* __restrict__ offsets,
                                                           int* __restrict__ cursor) {
    __shared__ int s[256];
    int tid = threadIdx.x;
    int i = blockIdx.x * 256 + tid;
    s[tid] = (i < N_NODES) ? counts[i] : 0;
    __syncthreads();
    for (int off = 1; off < 256; off <<= 1) {
        int x = s[tid];
        int a = (tid >= off) ? s[tid - off] : 0;
        __syncthreads();
        s[tid] = x + a;
        __syncthreads();
    }
    int excl = (tid > 0) ? s[tid - 1] : 0;
    int o = boffs[blockIdx.x] + excl;
    if (i < N_NODES) { offsets[i] = o; cursor[i] = o; }
    if (i == 0) offsets[N_NODES] = N_EDGES;
}

// ---------------- edge scores placed directly in CSR order --------------------
__device__ __forceinline__ float lrelu_exp(float x) {
    float y = (x > 0.f) ? x : NEG * x;
    return __expf(y);
}

__global__ __launch_bounds__(256) void edge_place_kernel(const int* __restrict__ src,
                                                         const int* __restrict__ dst,
                                                         const float* __restrict__ el,
                                                         const float* __restrict__ er,
                                                         int* __restrict__ cursor,
                                                         int* __restrict__ srcs,
                                                         float* __restrict__ w4s) {
    int e = blockIdx.x * blockDim.x + threadIdx.x;
    if (e >= N_EDGES) return;
    int u = src[e], v = dst[e];
    float4 l = *(const float4*)(el + (size_t)u * NH);
    float4 r = *(const float4*)(er + (size_t)v * NH);
    float4 s;
    s.x = lrelu_exp(l.x + r.x);
    s.y = lrelu_exp(l.y + r.y);
    s.z = lrelu_exp(l.z + r.z);
    s.w = lrelu_exp(l.w + r.w);
    int pos = atomicAdd(&cursor[v], 1);
    srcs[pos] = u;
    *(float4*)(w4s + (size_t)pos * NH) = s;
}

// ---------------- aggregation: one wave per dst, 4-edge software pipeline -----
__global__ __launch_bounds__(256) void agg_kernel(const unsigned short* __restrict__ ftb,
                                                  const float* __restrict__ w4s,
                                                  const int* __restrict__ srcs,
                                                  const int* __restrict__ offsets,
                                                  float* __restrict__ out) {
    int wv   = (blockIdx.x * blockDim.x + threadIdx.x) >> 6;  // node id
    int lane = threadIdx.x & 63;
    if (wv >= N_NODES) return;

    const int beg = offsets[wv];
    const int end = offsets[wv + 1];
    const int h   = lane >> 4;
    const size_t foff = (size_t)lane * 4;

    float4 acc = make_float4(0.f, 0.f, 0.f, 0.f);
    float dsum = 0.f;

    const int n4 = (end - beg) >> 2;   // full 4-edge blocks
    int u0, u1, u2, u3;
    if (n4 > 0) {
        const int* sp = srcs + beg;
        u0 = sp[0]; u1 = sp[1]; u2 = sp[2]; u3 = sp[3];
        for (int b = 0; b < n4; b++) {
            const int base = beg + b * 4;
            // preload next block's indices (breaks the idx->gather chain)
            int v0 = 0, v1 = 0, v2 = 0, v3 = 0;
            if (b + 1 < n4) {
                const int* np = srcs + base + 4;
                v0 = np[0]; v1 = np[1]; v2 = np[2]; v3 = np[3];
            }
            // 4 independent 512B gathers in flight
            ushort4 f0 = *(const ushort4*)(ftb + (size_t)u0 * HD + foff);
            ushort4 f1 = *(const ushort4*)(ftb + (size_t)u1 * HD + foff);
            ushort4 f2 = *(const ushort4*)(ftb + (size_t)u2 * HD + foff);
            ushort4 f3 = *(const ushort4*)(ftb + (size_t)u3 * HD + foff);
            float w0 = w4s[(size_t)(base + 0) * NH + h];
            float w1 = w4s[(size_t)(base + 1) * NH + h];
            float w2 = w4s[(size_t)(base + 2) * NH + h];
            float w3 = w4s[(size_t)(base + 3) * NH + h];
            acc.x += w0 * bf2f(f0.x) + w1 * bf2f(f1.x) + w2 * bf2f(f2.x) + w3 * bf2f(f3.x);
            acc.y += w0 * bf2f(f0.y) + w1 * bf2f(f1.y) + w2 * bf2f(f2.y) + w3 * bf2f(f3.y);
            acc.z += w0 * bf2f(f0.z) + w1 * bf2f(f1.z) + w2 * bf2f(f2.z) + w3 * bf2f(f3.z);
            acc.w += w0 * bf2f(f0.w) + w1 * bf2f(f1.w) + w2 * bf2f(f2.w) + w3 * bf2f(f3.w);
            dsum += (w0 + w1) + (w2 + w3);
            u0 = v0; u1 = v1; u2 = v2; u3 = v3;
        }
    }
    // tail (0..3 edges)
    for (int p = beg + n4 * 4; p < end; p++) {
        int u = srcs[p];
        float w = w4s[(size_t)p * NH + h];
        ushort4 f = *(const ushort4*)(ftb + (size_t)u * HD + foff);
        acc.x += w * bf2f(f.x);
        acc.y += w * bf2f(f.y);
        acc.z += w * bf2f(f.z);
        acc.w += w * bf2f(f.w);
        dsum += w;
    }

    float inv = (dsum > 0.f) ? (1.f / dsum) : 0.f;
    acc.x *= inv; acc.y *= inv; acc.z *= inv; acc.w *= inv;
    *(float4*)(out + (size_t)wv * HD + foff) = acc;
}

// ---------------- launch ----------------
extern "C" void kernel_launch(void* const* d_in, const int* in_sizes, int n_in,
                              void* d_out, int out_size, void* d_ws, size_t ws_size,
                              hipStream_t stream) {
    const float* feat   = (const float*)d_in[0];
    const float* W      = (const float*)d_in[1];
    const float* attn_l = (const float*)d_in[2];
    const float* attn_r = (const float*)d_in[3];
    const int*   src    = (const int*)d_in[4];
    const int*   dst    = (const int*)d_in[5];
    float* out = (float*)d_out;

    char* p = (char*)d_ws;
    auto alloc = [&](size_t bytes) -> char* {
        char* r = p;
        p += (bytes + 255) & ~(size_t)255;
        return r;
    };
    unsigned short* ftb     = (unsigned short*)alloc((size_t)N_NODES * HD * 2); // 25.6 MB
    unsigned short* Wtb     = (unsigned short*)alloc((size_t)IN_F * HD * 2);
    float*          el      = (float*)alloc((size_t)N_NODES * NH * 4);
    float*          er      = (float*)alloc((size_t)N_NODES * NH * 4);
    float*          w4s     = (float*)alloc((size_t)N_EDGES * NH * 4);   // 12.8 MB
    int*            srcs    = (int*)alloc((size_t)N_EDGES * 4);          // 3.2 MB
    int*            counts  = (int*)alloc((size_t)N_NODES * 4);
    int*            offsets = (int*)alloc((size_t)(N_NODES + 1) * 4);
    int*            cursor  = (int*)alloc((size_t)N_NODES * 4);
    int*            bsums   = (int*)alloc((size_t)NB * 4);
    int*            boffs   = (int*)alloc((size_t)NB * 4);

    // 1. zero counts
    zero_kernel<<<(N_NODES + 255) / 256, 256, 0, stream>>>(counts, N_NODES);
    // 2. per-dst counts
    count_kernel<<<(N_EDGES + 255) / 256, 256, 0, stream>>>(dst, counts);
    // 3. W -> Wt bf16
    wt_kernel<<<(IN_F * HD + 255) / 256, 256, 0, stream>>>(W, Wtb);
    // 4. ftb = bf16(feat @ W) (bf16 MFMA, 64x128 tile, reg-prefetch pipeline)
    dim3 ggrid((N_NODES + 63) / 64, HD / 128);
    gemm_kernel<<<ggrid, 256, 0, stream>>>(feat, Wtb, ftb);
    // 5. el / er (one wave per node)
    el_er_kernel<<<(N_NODES + 3) / 4, 256, 0, stream>>>(ftb, attn_l, attn_r, el, er);
    // 6. parallel 3-phase scan -> offsets, cursor
    partial_kernel<<<NB, 256, 0, stream>>>(counts, bsums);
    bscan_kernel<<<1, 256, 0, stream>>>(bsums, boffs);
    scatter_scan_kernel<<<NB, 256, 0, stream>>>(counts, boffs, offsets, cursor);
    // 7. edge scores placed in CSR order
    edge_place_kernel<<<(N_EDGES + 255) / 256, 256, 0, stream>>>(src, dst, el, er,
                                                                 cursor, srcs, w4s);
    // 8. aggregate per destination node (normalization fused)
    agg_kernel<<<(N_NODES + 3) / 4, 256, 0, stream>>>(ftb, w4s, srcs, offsets, out);
}